// Round 11
// baseline (6869.579 us; speedup 1.0000x reference)
//
#include <hip/hip_runtime.h>
#include <math.h>

typedef unsigned short u16;
typedef __attribute__((ext_vector_type(8))) short short8;
typedef __attribute__((ext_vector_type(4))) float f32x4;

#define LAYERS 8
#define D 1024
#define NH 16
#define DKH 64
#define DFF 4096
#define SEQ 66
#define TT 67
#define BATCH 256
#define ROWS (BATCH*TT)   /* 17152 = 134*128 */
#define VOCAB 4096
#define TP 80
#define KP 96
#define QS 3072           /* merged qkv row stride */

__device__ __forceinline__ float bf2f(u16 v){
  unsigned int u = ((unsigned int)v) << 16;
  return __builtin_bit_cast(float, u);
}
__device__ __forceinline__ u16 f2bf(float f){
  unsigned int u = __builtin_bit_cast(unsigned int, f);
  u += 0x7FFFu + ((u >> 16) & 1u);
  return (u16)(u >> 16);
}
__device__ __forceinline__ void gload16(const u16* g, u16* l){
  __builtin_amdgcn_global_load_lds((const __attribute__((address_space(1))) void*)g,
                                   (__attribute__((address_space(3))) void*)l, 16, 0, 0);
}

// ---------------- transpose + cast f32 -> bf16, all 6 weights of a layer ----------------
__device__ __forceinline__ void tc_tile(const float* __restrict__ src, u16* __restrict__ dst,
                                        int R, int C, int bx, int by, int tx, int ty){
  __shared__ float tile[32][33];
  const int c0 = bx * 32, r0 = by * 32;
  #pragma unroll
  for (int i = 0; i < 32; i += 8)
    tile[ty + i][tx] = src[(size_t)(r0 + ty + i) * C + (c0 + tx)];
  __syncthreads();
  #pragma unroll
  for (int i = 0; i < 32; i += 8)
    dst[(size_t)(c0 + ty + i) * R + (r0 + tx)] = f2bf(tile[tx][ty + i]);
}

__global__ void transpose6(const float* __restrict__ Wq, const float* __restrict__ Wk,
                           const float* __restrict__ Wv, const float* __restrict__ Wo,
                           const float* __restrict__ W1, const float* __restrict__ W2,
                           u16* __restrict__ WqkvT, u16* __restrict__ WoT,
                           u16* __restrict__ W1T, u16* __restrict__ W2T){
  const int tx = threadIdx.x, ty = threadIdx.y;
  int b = blockIdx.x;
  if (b < 4096){
    const int which = b >> 10, idx = b & 1023;
    const float* s = which == 0 ? Wq : which == 1 ? Wk : which == 2 ? Wv : Wo;
    u16* d = which == 3 ? WoT : WqkvT + which * D * D;
    tc_tile(s, d, D, D, idx & 31, idx >> 5, tx, ty);
  } else if (b < 8192){
    const int idx = b - 4096;
    tc_tile(W1, W1T, D, DFF, idx & 127, idx >> 7, tx, ty);
  } else {
    const int idx = b - 8192;
    tc_tile(W2, W2T, DFF, D, idx & 31, idx >> 5, tx, ty);
  }
}

__global__ void transpose_cast(const float* __restrict__ src, u16* __restrict__ dst,
                               int R, int C){
  tc_tile(src, dst, R, C, blockIdx.x, blockIdx.y, threadIdx.x, threadIdx.y);
}

// ---------------- embedding + positional encoding (bf16 stream only) ----------------
__global__ void embed_kernel(const int* __restrict__ x, const float* __restrict__ emb,
                             const float* __restrict__ pool, u16* __restrict__ hb){
  const int row = blockIdx.x;
  const int b = row / TT, t = row % TT;
  const int d0 = threadIdx.x * 4;
  float v[4];
  if (t == 0){
    const float4 p4 = *(const float4*)&pool[d0];
    v[0] = p4.x; v[1] = p4.y; v[2] = p4.z; v[3] = p4.w;
  } else {
    const int id = x[b * SEQ + (t - 1)];
    const float4 e4 = *(const float4*)&emb[(size_t)id * D + d0];
    v[0] = e4.x * 32.f; v[1] = e4.y * 32.f; v[2] = e4.z * 32.f; v[3] = e4.w * 32.f;
  }
  const float c = -logf(10000.f) / (float)D;
  float o[4];
  #pragma unroll
  for (int j = 0; j < 4; j++){
    const int d = d0 + j;
    const int p = d >> 1;
    const float freq = expf((float)(2 * p) * c);
    const float ang = (float)t * freq;
    const float pe = (d & 1) ? cosf(ang) : sinf(ang);
    o[j] = v[j] + pe;
  }
  const unsigned int lo = (unsigned)f2bf(o[0]) | ((unsigned)f2bf(o[1]) << 16);
  const unsigned int hi = (unsigned)f2bf(o[2]) | ((unsigned)f2bf(o[3]) << 16);
  *(uint2*)&hb[(size_t)row * D + d0] = make_uint2(lo, hi);
}

// ---------------- fused residual + LayerNorm (all-bf16 stream) ----------------
__global__ void ln_kernel(u16* __restrict__ hio, const u16* __restrict__ res,
                          const float* __restrict__ g, const float* __restrict__ bta){
  const int row = blockIdx.x;
  const int tid = threadIdx.x;
  const size_t off = (size_t)row * D + tid * 4;
  const uint2 a2 = *(const uint2*)&hio[off];
  const uint2 r2 = *(const uint2*)&res[off];
  const float s0 = bf2f((u16)(a2.x & 0xffff)) + bf2f((u16)(r2.x & 0xffff));
  const float s1 = bf2f((u16)(a2.x >> 16))    + bf2f((u16)(r2.x >> 16));
  const float s2 = bf2f((u16)(a2.y & 0xffff)) + bf2f((u16)(r2.y & 0xffff));
  const float s3 = bf2f((u16)(a2.y >> 16))    + bf2f((u16)(r2.y >> 16));
  float sum = s0 + s1 + s2 + s3;
  float sq = s0*s0 + s1*s1 + s2*s2 + s3*s3;
  #pragma unroll
  for (int m = 32; m >= 1; m >>= 1){ sum += __shfl_xor(sum, m); sq += __shfl_xor(sq, m); }
  __shared__ float red[2][4];
  const int w = tid >> 6;
  if ((tid & 63) == 0){ red[0][w] = sum; red[1][w] = sq; }
  __syncthreads();
  sum = red[0][0] + red[0][1] + red[0][2] + red[0][3];
  sq  = red[1][0] + red[1][1] + red[1][2] + red[1][3];
  const float mean = sum * (1.f / D);
  const float var = sq * (1.f / D) - mean * mean;
  const float rs = rsqrtf(var + 1e-5f);
  const float4 gv = *(const float4*)&g[tid * 4];
  const float4 bv = *(const float4*)&bta[tid * 4];
  const float o0 = (s0 - mean) * rs * gv.x + bv.x;
  const float o1 = (s1 - mean) * rs * gv.y + bv.y;
  const float o2 = (s2 - mean) * rs * gv.z + bv.z;
  const float o3 = (s3 - mean) * rs * gv.w + bv.w;
  const unsigned int lo = (unsigned)f2bf(o0) | ((unsigned)f2bf(o1) << 16);
  const unsigned int hi = (unsigned)f2bf(o2) | ((unsigned)f2bf(o3) << 16);
  *(uint2*)&hio[off] = make_uint2(lo, hi);
}

// ---------------- MFMA attention: one block (4 waves) per (batch, head) ----------------
__global__ __launch_bounds__(256) void attn_kernel(const u16* __restrict__ qkv,
    const float* __restrict__ rel, u16* __restrict__ ctxb){
  __shared__ u16 Qf[8 * 81 * 8];
  __shared__ u16 Kf[8 * 81 * 8];
  __shared__ u16 Vf[12 * 65 * 8];
  __shared__ u16 Pf[12 * 81 * 8];
  __shared__ float Ss[TP][84];
  const int bh = blockIdx.x;
  const int b = bh >> 4, hh = bh & 15;
  const int tid = threadIdx.x, w = tid >> 6, l = tid & 63;
  const size_t qvbase = (size_t)(b * TT) * QS + hh * DKH;
  const size_t obase  = (size_t)(b * TT) * D + hh * DKH;

  {
    const int r0 = tid >> 4, c4 = (tid & 15) * 4;
    const int g = c4 >> 3, e = c4 & 7;
    for (int r = r0; r < TP; r += 16){
      uint2 q2 = make_uint2(0u, 0u), k2 = make_uint2(0u, 0u);
      if (r < TT){
        q2 = *(const uint2*)&qkv[qvbase + (size_t)r * QS + c4];
        k2 = *(const uint2*)&qkv[qvbase + 1024 + (size_t)r * QS + c4];
      }
      *(uint2*)&Qf[(g * 81 + r) * 8 + e] = q2;
      *(uint2*)&Kf[(g * 81 + r) * 8 + e] = k2;
    }
    for (int j = r0; j < KP; j += 16){
      u16 v4[4] = {0, 0, 0, 0};
      if (j < TT) *(uint2*)v4 = *(const uint2*)&qkv[qvbase + 2048 + (size_t)j * QS + c4];
      const int gg = j >> 3, ee = j & 7;
      #pragma unroll
      for (int d = 0; d < 4; d++)
        Vf[(gg * 65 + (c4 + d)) * 8 + ee] = v4[d];
    }
  }
  __syncthreads();

  const int fr = l & 15, gg = l >> 4;
  for (int p = w; p < 25; p += 4){
    const int rt = p / 5, ct = p % 5;
    f32x4 acc = {};
    #pragma unroll
    for (int kk = 0; kk < 2; kk++){
      const short8 a  = *(const short8*)&Qf[((kk * 4 + gg) * 81 + rt * 16 + fr) * 8];
      const short8 bf = *(const short8*)&Kf[((kk * 4 + gg) * 81 + ct * 16 + fr) * 8];
      acc = __builtin_amdgcn_mfma_f32_16x16x32_bf16(a, bf, acc, 0, 0, 0);
    }
    const int col = ct * 16 + fr;
    #pragma unroll
    for (int r = 0; r < 4; r++){
      const int row = rt * 16 + gg * 4 + r;
      float sv = -1e30f;
      if (row < TT && col < TT)
        sv = acc[r] * 0.125f + rel[((size_t)hh * 78 + row) * 78 + col];
      Ss[row][col] = sv;
    }
  }
  __syncthreads();

  for (int row = w; row < TP; row += 4){
    const float s1 = Ss[row][l];
    const float s2 = (l < 16) ? Ss[row][64 + l] : -1e30f;
    float mx = fmaxf(s1, s2);
    #pragma unroll
    for (int m = 32; m >= 1; m >>= 1) mx = fmaxf(mx, __shfl_xor(mx, m));
    const float e1 = __expf(s1 - mx);
    const float e2 = (l < 16) ? __expf(s2 - mx) : 0.f;
    float sum = e1 + e2;
    #pragma unroll
    for (int m = 32; m >= 1; m >>= 1) sum += __shfl_xor(sum, m);
    const float inv = 1.f / sum;
    Pf[((l >> 3) * 81 + row) * 8 + (l & 7)] = f2bf(e1 * inv);
    if (l < 16){
      Pf[((8  + (l >> 3)) * 81 + row) * 8 + (l & 7)] = f2bf(e2 * inv);
      Pf[((10 + (l >> 3)) * 81 + row) * 8 + (l & 7)] = 0;
    }
  }
  __syncthreads();

  for (int p = w; p < 20; p += 4){
    const int rt = p >> 2, ct = p & 3;
    f32x4 acc = {};
    #pragma unroll
    for (int kk = 0; kk < 3; kk++){
      const short8 a  = *(const short8*)&Pf[((kk * 4 + gg) * 81 + rt * 16 + fr) * 8];
      const short8 bf = *(const short8*)&Vf[((kk * 4 + gg) * 65 + ct * 16 + fr) * 8];
      acc = __builtin_amdgcn_mfma_f32_16x16x32_bf16(a, bf, acc, 0, 0, 0);
    }
    #pragma unroll
    for (int r = 0; r < 4; r++){
      const int row = rt * 16 + gg * 4 + r;
      if (row < TT)
        ctxb[obase + (size_t)row * D + ct * 16 + fr] = f2bf(acc[r]);
    }
  }
}

// ---------------- 128x128 bf16 MFMA GEMM: dbuf + stage-ahead, XCD-chunked swizzle,
// nontemporal C-stores (keep write stream out of L2/L3 so B panels stay resident).
template<int OBF16, int BIAS, int GELU>
__global__ __launch_bounds__(256, 4) void gemm_bt(
    const u16* __restrict__ A, int lda,
    const u16* __restrict__ Bt,
    void* __restrict__ Cv, int ldc,
    const float* __restrict__ bias, int K, int nby)
{
  __shared__ u16 As[2][128 * 32];
  __shared__ u16 Bs[2][128 * 32];
  const int nwg = gridDim.x, bid = blockIdx.x;
  const int q8 = nwg >> 3, r8 = nwg & 7;
  const int xcd = bid & 7, off = bid >> 3;
  const int wg = (xcd < r8 ? xcd * (q8 + 1) : r8 * (q8 + 1) + (xcd - r8) * q8) + off;
  const int m0 = (wg / nby) * 128, n0 = (wg % nby) * 128;

  const int tid = threadIdx.x;
  const int l = tid & 63, w = tid >> 6;
  const int wr = w >> 1, wc = w & 1;
  f32x4 acc[4][4] = {};
  const int lr = l >> 2;
  const int lseg = (l & 3) * 8;
  const u16* ga0 = A + (size_t)(m0 + w * 32 + lr) * lda + lseg;
  const u16* ga1 = A + (size_t)(m0 + w * 32 + 16 + lr) * lda + lseg;
  const u16* gb0 = Bt + (size_t)(n0 + w * 32 + lr) * K + lseg;
  const u16* gb1 = Bt + (size_t)(n0 + w * 32 + 16 + lr) * K + lseg;
  const int fr = l & 15, kg = (l >> 4) * 8;

#define STAGE(sel, kc) do { \
    gload16(ga0 + (kc), &As[sel][(w * 32) * 32]); \
    gload16(ga1 + (kc), &As[sel][(w * 32 + 16) * 32]); \
    gload16(gb0 + (kc), &Bs[sel][(w * 32) * 32]); \
    gload16(gb1 + (kc), &Bs[sel][(w * 32 + 16) * 32]); \
  } while (0)

  const int nkt = K >> 5;
  STAGE(0, 0);
  __syncthreads();
  int cur = 0;
  #pragma unroll 1
  for (int kt = 0; kt < nkt; ++kt){
    if (kt + 1 < nkt) STAGE(cur ^ 1, (kt + 1) * 32);
    short8 af[4], bf[4];
    #pragma unroll
    for (int i = 0; i < 4; i++){
      af[i] = *(const short8*)&As[cur][(wr * 64 + i * 16 + fr) * 32 + kg];
      bf[i] = *(const short8*)&Bs[cur][(wc * 64 + i * 16 + fr) * 32 + kg];
    }
    #pragma unroll
    for (int i = 0; i < 4; i++)
      #pragma unroll
      for (int j = 0; j < 4; j++)
        acc[i][j] = __builtin_amdgcn_mfma_f32_16x16x32_bf16(af[i], bf[j], acc[i][j], 0, 0, 0);
    __syncthreads();
    cur ^= 1;
  }
#undef STAGE

  const int rg = (l >> 4) * 4;
  #pragma unroll
  for (int i = 0; i < 4; i++){
    #pragma unroll
    for (int j = 0; j < 4; j++){
      const int col = n0 + wc * 64 + j * 16 + fr;
      const float bv = BIAS ? bias[col] : 0.f;
      #pragma unroll
      for (int r = 0; r < 4; r++){
        const int row = m0 + wr * 64 + i * 16 + rg + r;
        float xv = acc[i][j][r] + bv;
        if (GELU) xv = 0.5f * xv * (1.f + erff(xv * 0.70710678118f));
        if (OBF16) __builtin_nontemporal_store(f2bf(xv), &((u16*)Cv)[(size_t)row * ldc + col]);
        else       __builtin_nontemporal_store(xv, &((float*)Cv)[(size_t)row * ldc + col]);
      }
    }
  }
}

extern "C" void kernel_launch(void* const* d_in, const int* in_sizes, int n_in,
                              void* d_out, int out_size, void* d_ws, size_t ws_size,
                              hipStream_t stream) {
  const int*   x       = (const int*)  d_in[0];
  const float* emb     = (const float*)d_in[1];
  const float* pool    = (const float*)d_in[2];
  const float* Wq      = (const float*)d_in[3];
  const float* Wk      = (const float*)d_in[4];
  const float* Wv      = (const float*)d_in[5];
  const float* Wo      = (const float*)d_in[6];
  const float* rel     = (const float*)d_in[7];
  const float* ln1_g   = (const float*)d_in[8];
  const float* ln1_b   = (const float*)d_in[9];
  const float* ln2_g   = (const float*)d_in[10];
  const float* ln2_b   = (const float*)d_in[11];
  const float* W1      = (const float*)d_in[12];
  const float* b1      = (const float*)d_in[13];
  const float* W2      = (const float*)d_in[14];
  const float* b2      = (const float*)d_in[15];
  const float* Wout    = (const float*)d_in[16];
  const float* bout    = (const float*)d_in[17];
  float* out = (float*)d_out;

  const size_t SZ_WDD  = (size_t)D * D * 2;
  const size_t SZ_WDF  = (size_t)D * DFF * 2;
  const size_t SZ_HB   = (size_t)ROWS * D * 2;
  const size_t need = 4*SZ_WDD + 3*SZ_WDF + 6*SZ_HB;
  if (ws_size < need) return;

  char* p = (char*)d_ws;
  u16* WqkvT = (u16*)p; p += 3*SZ_WDD;
  u16* WoT   = (u16*)p; p += SZ_WDD;
  u16* W1T   = (u16*)p; p += SZ_WDF;
  u16* W2T   = (u16*)p; p += SZ_WDF;
  u16* WouT  = (u16*)p; p += SZ_WDF;
  u16* hb    = (u16*)p; p += SZ_HB;
  u16* qkv   = (u16*)p; p += 3*SZ_HB;    // [ROWS][3072]
  u16* ctxb  = (u16*)p; p += SZ_HB;
  u16* gb    = qkv;                       // FFN hidden aliases qkv+ctx
  u16* tmpb  = (u16*)p; p += SZ_HB;       // residual-branch bf16

  dim3 tb(32, 8);
  transpose_cast<<<dim3(VOCAB/32, D/32), tb, 0, stream>>>(Wout, WouT, D, VOCAB);
  embed_kernel<<<ROWS, 256, 0, stream>>>(x, emb, pool, hb);

  const int MB = ROWS / 128;   // 134
  for (int l = 0; l < LAYERS; ++l){
    const size_t wo = (size_t)l * D * D;
    const size_t wf = (size_t)l * D * DFF;
    transpose6<<<12288, tb, 0, stream>>>(Wq + wo, Wk + wo, Wv + wo, Wo + wo,
                                         W1 + wf, W2 + wf, WqkvT, WoT, W1T, W2T);

    gemm_bt<1,0,0><<<MB * (QS/128),  256, 0, stream>>>(hb, D, WqkvT, qkv, QS, nullptr, D, QS/128);
    attn_kernel<<<BATCH*NH, 256, 0, stream>>>(qkv, rel + (size_t)l*NH*78*78, ctxb);
    gemm_bt<1,0,0><<<MB * (D/128),   256, 0, stream>>>(ctxb, D, WoT, tmpb, D, nullptr, D, D/128);
    ln_kernel<<<ROWS, 256, 0, stream>>>(hb, tmpb, ln1_g + l*D, ln1_b + l*D);
    gemm_bt<1,1,1><<<MB * (DFF/128), 256, 0, stream>>>(hb, D, W1T, gb, DFF, b1 + l*DFF, D, DFF/128);
    gemm_bt<1,1,0><<<MB * (D/128),   256, 0, stream>>>(gb, DFF, W2T, tmpb, D, b2 + l*D, DFF, D/128);
    ln_kernel<<<ROWS, 256, 0, stream>>>(hb, tmpb, ln2_g + l*D, ln2_b + l*D);
  }
  gemm_bt<0,1,0><<<(BATCH/128) * (VOCAB/128), 256, 0, stream>>>(
      hb, TT * D, WouT, out, VOCAB, bout, D, VOCAB/128);
}

// Round 12
// 6307.477 us; speedup vs baseline: 1.0891x; 1.0891x over previous
//
#include <hip/hip_runtime.h>
#include <math.h>

typedef unsigned short u16;
typedef __attribute__((ext_vector_type(8))) short short8;
typedef __attribute__((ext_vector_type(4))) float f32x4;

#define LAYERS 8
#define D 1024
#define NH 16
#define DKH 64
#define DFF 4096
#define SEQ 66
#define TT 67
#define BATCH 256
#define ROWS (BATCH*TT)   /* 17152 = 134*128 */
#define VOCAB 4096
#define TP 80
#define KP 96
#define QS 3072           /* merged qkv row stride */

__device__ __forceinline__ float bf2f(u16 v){
  unsigned int u = ((unsigned int)v) << 16;
  return __builtin_bit_cast(float, u);
}
__device__ __forceinline__ u16 f2bf(float f){
  unsigned int u = __builtin_bit_cast(unsigned int, f);
  u += 0x7FFFu + ((u >> 16) & 1u);
  return (u16)(u >> 16);
}
__device__ __forceinline__ void gload16(const u16* g, u16* l){
  __builtin_amdgcn_global_load_lds((const __attribute__((address_space(1))) void*)g,
                                   (__attribute__((address_space(3))) void*)l, 16, 0, 0);
}

// ---------------- transpose + cast f32 -> bf16, all 6 weights of a layer ----------------
__device__ __forceinline__ void tc_tile(const float* __restrict__ src, u16* __restrict__ dst,
                                        int R, int C, int bx, int by, int tx, int ty){
  __shared__ float tile[32][33];
  const int c0 = bx * 32, r0 = by * 32;
  #pragma unroll
  for (int i = 0; i < 32; i += 8)
    tile[ty + i][tx] = src[(size_t)(r0 + ty + i) * C + (c0 + tx)];
  __syncthreads();
  #pragma unroll
  for (int i = 0; i < 32; i += 8)
    dst[(size_t)(c0 + ty + i) * R + (r0 + tx)] = f2bf(tile[tx][ty + i]);
}

__global__ void transpose6(const float* __restrict__ Wq, const float* __restrict__ Wk,
                           const float* __restrict__ Wv, const float* __restrict__ Wo,
                           const float* __restrict__ W1, const float* __restrict__ W2,
                           u16* __restrict__ WqkvT, u16* __restrict__ WoT,
                           u16* __restrict__ W1T, u16* __restrict__ W2T){
  const int tx = threadIdx.x, ty = threadIdx.y;
  int b = blockIdx.x;
  if (b < 4096){
    const int which = b >> 10, idx = b & 1023;
    const float* s = which == 0 ? Wq : which == 1 ? Wk : which == 2 ? Wv : Wo;
    u16* d = which == 3 ? WoT : WqkvT + which * D * D;
    tc_tile(s, d, D, D, idx & 31, idx >> 5, tx, ty);
  } else if (b < 8192){
    const int idx = b - 4096;
    tc_tile(W1, W1T, D, DFF, idx & 127, idx >> 7, tx, ty);
  } else {
    const int idx = b - 8192;
    tc_tile(W2, W2T, DFF, D, idx & 31, idx >> 5, tx, ty);
  }
}

__global__ void transpose_cast(const float* __restrict__ src, u16* __restrict__ dst,
                               int R, int C){
  tc_tile(src, dst, R, C, blockIdx.x, blockIdx.y, threadIdx.x, threadIdx.y);
}

// ---------------- embedding + positional encoding (bf16 stream only) ----------------
__global__ void embed_kernel(const int* __restrict__ x, const float* __restrict__ emb,
                             const float* __restrict__ pool, u16* __restrict__ hb){
  const int row = blockIdx.x;
  const int b = row / TT, t = row % TT;
  const int d0 = threadIdx.x * 4;
  float v[4];
  if (t == 0){
    const float4 p4 = *(const float4*)&pool[d0];
    v[0] = p4.x; v[1] = p4.y; v[2] = p4.z; v[3] = p4.w;
  } else {
    const int id = x[b * SEQ + (t - 1)];
    const float4 e4 = *(const float4*)&emb[(size_t)id * D + d0];
    v[0] = e4.x * 32.f; v[1] = e4.y * 32.f; v[2] = e4.z * 32.f; v[3] = e4.w * 32.f;
  }
  const float c = -logf(10000.f) / (float)D;
  float o[4];
  #pragma unroll
  for (int j = 0; j < 4; j++){
    const int d = d0 + j;
    const int p = d >> 1;
    const float freq = expf((float)(2 * p) * c);
    const float ang = (float)t * freq;
    const float pe = (d & 1) ? cosf(ang) : sinf(ang);
    o[j] = v[j] + pe;
  }
  const unsigned int lo = (unsigned)f2bf(o[0]) | ((unsigned)f2bf(o[1]) << 16);
  const unsigned int hi = (unsigned)f2bf(o[2]) | ((unsigned)f2bf(o[3]) << 16);
  *(uint2*)&hb[(size_t)row * D + d0] = make_uint2(lo, hi);
}

// ---------------- fused residual + LayerNorm (all-bf16 stream) ----------------
__global__ void ln_kernel(u16* __restrict__ hio, const u16* __restrict__ res,
                          const float* __restrict__ g, const float* __restrict__ bta){
  const int row = blockIdx.x;
  const int tid = threadIdx.x;
  const size_t off = (size_t)row * D + tid * 4;
  const uint2 a2 = *(const uint2*)&hio[off];
  const uint2 r2 = *(const uint2*)&res[off];
  const float s0 = bf2f((u16)(a2.x & 0xffff)) + bf2f((u16)(r2.x & 0xffff));
  const float s1 = bf2f((u16)(a2.x >> 16))    + bf2f((u16)(r2.x >> 16));
  const float s2 = bf2f((u16)(a2.y & 0xffff)) + bf2f((u16)(r2.y & 0xffff));
  const float s3 = bf2f((u16)(a2.y >> 16))    + bf2f((u16)(r2.y >> 16));
  float sum = s0 + s1 + s2 + s3;
  float sq = s0*s0 + s1*s1 + s2*s2 + s3*s3;
  #pragma unroll
  for (int m = 32; m >= 1; m >>= 1){ sum += __shfl_xor(sum, m); sq += __shfl_xor(sq, m); }
  __shared__ float red[2][4];
  const int w = tid >> 6;
  if ((tid & 63) == 0){ red[0][w] = sum; red[1][w] = sq; }
  __syncthreads();
  sum = red[0][0] + red[0][1] + red[0][2] + red[0][3];
  sq  = red[1][0] + red[1][1] + red[1][2] + red[1][3];
  const float mean = sum * (1.f / D);
  const float var = sq * (1.f / D) - mean * mean;
  const float rs = rsqrtf(var + 1e-5f);
  const float4 gv = *(const float4*)&g[tid * 4];
  const float4 bv = *(const float4*)&bta[tid * 4];
  const float o0 = (s0 - mean) * rs * gv.x + bv.x;
  const float o1 = (s1 - mean) * rs * gv.y + bv.y;
  const float o2 = (s2 - mean) * rs * gv.z + bv.z;
  const float o3 = (s3 - mean) * rs * gv.w + bv.w;
  const unsigned int lo = (unsigned)f2bf(o0) | ((unsigned)f2bf(o1) << 16);
  const unsigned int hi = (unsigned)f2bf(o2) | ((unsigned)f2bf(o3) << 16);
  *(uint2*)&hio[off] = make_uint2(lo, hi);
}

// ---------------- MFMA attention: one block (4 waves) per (batch, head) ----------------
__global__ __launch_bounds__(256) void attn_kernel(const u16* __restrict__ qkv,
    const float* __restrict__ rel, u16* __restrict__ ctxb){
  __shared__ u16 Qf[8 * 81 * 8];
  __shared__ u16 Kf[8 * 81 * 8];
  __shared__ u16 Vf[12 * 65 * 8];
  __shared__ u16 Pf[12 * 81 * 8];
  __shared__ float Ss[TP][84];
  const int bh = blockIdx.x;
  const int b = bh >> 4, hh = bh & 15;
  const int tid = threadIdx.x, w = tid >> 6, l = tid & 63;
  const size_t qvbase = (size_t)(b * TT) * QS + hh * DKH;
  const size_t obase  = (size_t)(b * TT) * D + hh * DKH;

  {
    const int r0 = tid >> 4, c4 = (tid & 15) * 4;
    const int g = c4 >> 3, e = c4 & 7;
    for (int r = r0; r < TP; r += 16){
      uint2 q2 = make_uint2(0u, 0u), k2 = make_uint2(0u, 0u);
      if (r < TT){
        q2 = *(const uint2*)&qkv[qvbase + (size_t)r * QS + c4];
        k2 = *(const uint2*)&qkv[qvbase + 1024 + (size_t)r * QS + c4];
      }
      *(uint2*)&Qf[(g * 81 + r) * 8 + e] = q2;
      *(uint2*)&Kf[(g * 81 + r) * 8 + e] = k2;
    }
    for (int j = r0; j < KP; j += 16){
      u16 v4[4] = {0, 0, 0, 0};
      if (j < TT) *(uint2*)v4 = *(const uint2*)&qkv[qvbase + 2048 + (size_t)j * QS + c4];
      const int gg = j >> 3, ee = j & 7;
      #pragma unroll
      for (int d = 0; d < 4; d++)
        Vf[(gg * 65 + (c4 + d)) * 8 + ee] = v4[d];
    }
  }
  __syncthreads();

  const int fr = l & 15, gg = l >> 4;
  for (int p = w; p < 25; p += 4){
    const int rt = p / 5, ct = p % 5;
    f32x4 acc = {};
    #pragma unroll
    for (int kk = 0; kk < 2; kk++){
      const short8 a  = *(const short8*)&Qf[((kk * 4 + gg) * 81 + rt * 16 + fr) * 8];
      const short8 bf = *(const short8*)&Kf[((kk * 4 + gg) * 81 + ct * 16 + fr) * 8];
      acc = __builtin_amdgcn_mfma_f32_16x16x32_bf16(a, bf, acc, 0, 0, 0);
    }
    const int col = ct * 16 + fr;
    #pragma unroll
    for (int r = 0; r < 4; r++){
      const int row = rt * 16 + gg * 4 + r;
      float sv = -1e30f;
      if (row < TT && col < TT)
        sv = acc[r] * 0.125f + rel[((size_t)hh * 78 + row) * 78 + col];
      Ss[row][col] = sv;
    }
  }
  __syncthreads();

  for (int row = w; row < TP; row += 4){
    const float s1 = Ss[row][l];
    const float s2 = (l < 16) ? Ss[row][64 + l] : -1e30f;
    float mx = fmaxf(s1, s2);
    #pragma unroll
    for (int m = 32; m >= 1; m >>= 1) mx = fmaxf(mx, __shfl_xor(mx, m));
    const float e1 = __expf(s1 - mx);
    const float e2 = (l < 16) ? __expf(s2 - mx) : 0.f;
    float sum = e1 + e2;
    #pragma unroll
    for (int m = 32; m >= 1; m >>= 1) sum += __shfl_xor(sum, m);
    const float inv = 1.f / sum;
    Pf[((l >> 3) * 81 + row) * 8 + (l & 7)] = f2bf(e1 * inv);
    if (l < 16){
      Pf[((8  + (l >> 3)) * 81 + row) * 8 + (l & 7)] = f2bf(e2 * inv);
      Pf[((10 + (l >> 3)) * 81 + row) * 8 + (l & 7)] = 0;
    }
  }
  __syncthreads();

  for (int p = w; p < 20; p += 4){
    const int rt = p >> 2, ct = p & 3;
    f32x4 acc = {};
    #pragma unroll
    for (int kk = 0; kk < 3; kk++){
      const short8 a  = *(const short8*)&Pf[((kk * 4 + gg) * 81 + rt * 16 + fr) * 8];
      const short8 bf = *(const short8*)&Vf[((kk * 4 + gg) * 65 + ct * 16 + fr) * 8];
      acc = __builtin_amdgcn_mfma_f32_16x16x32_bf16(a, bf, acc, 0, 0, 0);
    }
    #pragma unroll
    for (int r = 0; r < 4; r++){
      const int row = rt * 16 + gg * 4 + r;
      if (row < TT)
        ctxb[obase + (size_t)row * D + ct * 16 + fr] = f2bf(acc[r]);
    }
  }
}

// ---------------- 128x128 bf16 MFMA GEMM: dbuf + stage-ahead, XCD-chunked swizzle ----------------
template<int OBF16, int BIAS, int GELU>
__global__ __launch_bounds__(256, 4) void gemm_bt(
    const u16* __restrict__ A, int lda,
    const u16* __restrict__ Bt,
    void* __restrict__ Cv, int ldc,
    const float* __restrict__ bias, int K, int nby)
{
  __shared__ u16 As[2][128 * 32];
  __shared__ u16 Bs[2][128 * 32];
  const int nwg = gridDim.x, bid = blockIdx.x;
  const int q8 = nwg >> 3, r8 = nwg & 7;
  const int xcd = bid & 7, off = bid >> 3;
  const int wg = (xcd < r8 ? xcd * (q8 + 1) : r8 * (q8 + 1) + (xcd - r8) * q8) + off;
  const int m0 = (wg / nby) * 128, n0 = (wg % nby) * 128;

  const int tid = threadIdx.x;
  const int l = tid & 63, w = tid >> 6;
  const int wr = w >> 1, wc = w & 1;
  f32x4 acc[4][4] = {};
  const int lr = l >> 2;
  const int lseg = (l & 3) * 8;
  const u16* ga0 = A + (size_t)(m0 + w * 32 + lr) * lda + lseg;
  const u16* ga1 = A + (size_t)(m0 + w * 32 + 16 + lr) * lda + lseg;
  const u16* gb0 = Bt + (size_t)(n0 + w * 32 + lr) * K + lseg;
  const u16* gb1 = Bt + (size_t)(n0 + w * 32 + 16 + lr) * K + lseg;
  const int fr = l & 15, kg = (l >> 4) * 8;

#define STAGE(sel, kc) do { \
    gload16(ga0 + (kc), &As[sel][(w * 32) * 32]); \
    gload16(ga1 + (kc), &As[sel][(w * 32 + 16) * 32]); \
    gload16(gb0 + (kc), &Bs[sel][(w * 32) * 32]); \
    gload16(gb1 + (kc), &Bs[sel][(w * 32 + 16) * 32]); \
  } while (0)

  const int nkt = K >> 5;
  STAGE(0, 0);
  __syncthreads();
  int cur = 0;
  #pragma unroll 1
  for (int kt = 0; kt < nkt; ++kt){
    if (kt + 1 < nkt) STAGE(cur ^ 1, (kt + 1) * 32);
    short8 af[4], bf[4];
    #pragma unroll
    for (int i = 0; i < 4; i++){
      af[i] = *(const short8*)&As[cur][(wr * 64 + i * 16 + fr) * 32 + kg];
      bf[i] = *(const short8*)&Bs[cur][(wc * 64 + i * 16 + fr) * 32 + kg];
    }
    #pragma unroll
    for (int i = 0; i < 4; i++)
      #pragma unroll
      for (int j = 0; j < 4; j++)
        acc[i][j] = __builtin_amdgcn_mfma_f32_16x16x32_bf16(af[i], bf[j], acc[i][j], 0, 0, 0);
    __syncthreads();
    cur ^= 1;
  }
#undef STAGE

  const int rg = (l >> 4) * 4;
  #pragma unroll
  for (int i = 0; i < 4; i++){
    #pragma unroll
    for (int j = 0; j < 4; j++){
      const int col = n0 + wc * 64 + j * 16 + fr;
      const float bv = BIAS ? bias[col] : 0.f;
      #pragma unroll
      for (int r = 0; r < 4; r++){
        const int row = m0 + wr * 64 + i * 16 + rg + r;
        float xv = acc[i][j][r] + bv;
        if (GELU) xv = 0.5f * xv * (1.f + erff(xv * 0.70710678118f));
        if (OBF16) ((u16*)Cv)[(size_t)row * ldc + col] = f2bf(xv);
        else       ((float*)Cv)[(size_t)row * ldc + col] = xv;
      }
    }
  }
}

extern "C" void kernel_launch(void* const* d_in, const int* in_sizes, int n_in,
                              void* d_out, int out_size, void* d_ws, size_t ws_size,
                              hipStream_t stream) {
  const int*   x       = (const int*)  d_in[0];
  const float* emb     = (const float*)d_in[1];
  const float* pool    = (const float*)d_in[2];
  const float* Wq      = (const float*)d_in[3];
  const float* Wk      = (const float*)d_in[4];
  const float* Wv      = (const float*)d_in[5];
  const float* Wo      = (const float*)d_in[6];
  const float* rel     = (const float*)d_in[7];
  const float* ln1_g   = (const float*)d_in[8];
  const float* ln1_b   = (const float*)d_in[9];
  const float* ln2_g   = (const float*)d_in[10];
  const float* ln2_b   = (const float*)d_in[11];
  const float* W1      = (const float*)d_in[12];
  const float* b1      = (const float*)d_in[13];
  const float* W2      = (const float*)d_in[14];
  const float* b2      = (const float*)d_in[15];
  const float* Wout    = (const float*)d_in[16];
  const float* bout    = (const float*)d_in[17];
  float* out = (float*)d_out;

  const size_t SZ_WDD  = (size_t)D * D * 2;
  const size_t SZ_WDF  = (size_t)D * DFF * 2;
  const size_t SZ_HB   = (size_t)ROWS * D * 2;
  const size_t need = 4*SZ_WDD + 3*SZ_WDF + 6*SZ_HB;
  if (ws_size < need) return;

  char* p = (char*)d_ws;
  u16* WqkvT = (u16*)p; p += 3*SZ_WDD;
  u16* WoT   = (u16*)p; p += SZ_WDD;
  u16* W1T   = (u16*)p; p += SZ_WDF;
  u16* W2T   = (u16*)p; p += SZ_WDF;
  u16* WouT  = (u16*)p; p += SZ_WDF;
  u16* hb    = (u16*)p; p += SZ_HB;
  u16* qkv   = (u16*)p; p += 3*SZ_HB;    // [ROWS][3072]
  u16* ctxb  = (u16*)p; p += SZ_HB;
  u16* gb    = qkv;                       // FFN hidden aliases qkv+ctx
  u16* tmpb  = (u16*)p; p += SZ_HB;       // residual-branch bf16

  dim3 tb(32, 8);
  transpose_cast<<<dim3(VOCAB/32, D/32), tb, 0, stream>>>(Wout, WouT, D, VOCAB);
  embed_kernel<<<ROWS, 256, 0, stream>>>(x, emb, pool, hb);

  const int MB = ROWS / 128;   // 134
  for (int l = 0; l < LAYERS; ++l){
    const size_t wo = (size_t)l * D * D;
    const size_t wf = (size_t)l * D * DFF;
    transpose6<<<12288, tb, 0, stream>>>(Wq + wo, Wk + wo, Wv + wo, Wo + wo,
                                         W1 + wf, W2 + wf, WqkvT, WoT, W1T, W2T);

    gemm_bt<1,0,0><<<MB * (QS/128),  256, 0, stream>>>(hb, D, WqkvT, qkv, QS, nullptr, D, QS/128);
    attn_kernel<<<BATCH*NH, 256, 0, stream>>>(qkv, rel + (size_t)l*NH*78*78, ctxb);
    gemm_bt<1,0,0><<<MB * (D/128),   256, 0, stream>>>(ctxb, D, WoT, tmpb, D, nullptr, D, D/128);
    ln_kernel<<<ROWS, 256, 0, stream>>>(hb, tmpb, ln1_g + l*D, ln1_b + l*D);
    gemm_bt<1,1,1><<<MB * (DFF/128), 256, 0, stream>>>(hb, D, W1T, gb, DFF, b1 + l*DFF, D, DFF/128);
    gemm_bt<1,1,0><<<MB * (D/128),   256, 0, stream>>>(gb, DFF, W2T, tmpb, D, b2 + l*D, DFF, D/128);
    ln_kernel<<<ROWS, 256, 0, stream>>>(hb, tmpb, ln2_g + l*D, ln2_b + l*D);
  }
  gemm_bt<0,1,0><<<(BATCH/128) * (VOCAB/128), 256, 0, stream>>>(
      hb, TT * D, WouT, out, VOCAB, bout, D, VOCAB/128);
}

// Round 13
// 6269.036 us; speedup vs baseline: 1.0958x; 1.0061x over previous
//
#include <hip/hip_runtime.h>
#include <math.h>

typedef unsigned short u16;
typedef __attribute__((ext_vector_type(8))) short short8;
typedef __attribute__((ext_vector_type(4))) float f32x4;

#define LAYERS 8
#define D 1024
#define NH 16
#define DKH 64
#define DFF 4096
#define SEQ 66
#define TT 67
#define BATCH 256
#define ROWS (BATCH*TT)   /* 17152 = 134*128 */
#define VOCAB 4096
#define TP 80
#define KP 96
#define QS 3072           /* merged qkv row stride */

__device__ __forceinline__ float bf2f(u16 v){
  unsigned int u = ((unsigned int)v) << 16;
  return __builtin_bit_cast(float, u);
}
__device__ __forceinline__ u16 f2bf(float f){
  unsigned int u = __builtin_bit_cast(unsigned int, f);
  u += 0x7FFFu + ((u >> 16) & 1u);
  return (u16)(u >> 16);
}
__device__ __forceinline__ void gload16(const u16* g, u16* l){
  __builtin_amdgcn_global_load_lds((const __attribute__((address_space(1))) void*)g,
                                   (__attribute__((address_space(3))) void*)l, 16, 0, 0);
}

// ---------------- transpose + cast f32 -> bf16, all 6 weights of a layer ----------------
__device__ __forceinline__ void tc_tile(const float* __restrict__ src, u16* __restrict__ dst,
                                        int R, int C, int bx, int by, int tx, int ty){
  __shared__ float tile[32][33];
  const int c0 = bx * 32, r0 = by * 32;
  #pragma unroll
  for (int i = 0; i < 32; i += 8)
    tile[ty + i][tx] = src[(size_t)(r0 + ty + i) * C + (c0 + tx)];
  __syncthreads();
  #pragma unroll
  for (int i = 0; i < 32; i += 8)
    dst[(size_t)(c0 + ty + i) * R + (r0 + tx)] = f2bf(tile[tx][ty + i]);
}

__global__ void transpose6(const float* __restrict__ Wq, const float* __restrict__ Wk,
                           const float* __restrict__ Wv, const float* __restrict__ Wo,
                           const float* __restrict__ W1, const float* __restrict__ W2,
                           u16* __restrict__ WqkvT, u16* __restrict__ WoT,
                           u16* __restrict__ W1T, u16* __restrict__ W2T){
  const int tx = threadIdx.x, ty = threadIdx.y;
  int b = blockIdx.x;
  if (b < 4096){
    const int which = b >> 10, idx = b & 1023;
    const float* s = which == 0 ? Wq : which == 1 ? Wk : which == 2 ? Wv : Wo;
    u16* d = which == 3 ? WoT : WqkvT + which * D * D;
    tc_tile(s, d, D, D, idx & 31, idx >> 5, tx, ty);
  } else if (b < 8192){
    const int idx = b - 4096;
    tc_tile(W1, W1T, D, DFF, idx & 127, idx >> 7, tx, ty);
  } else {
    const int idx = b - 8192;
    tc_tile(W2, W2T, DFF, D, idx & 31, idx >> 5, tx, ty);
  }
}

__global__ void transpose_cast(const float* __restrict__ src, u16* __restrict__ dst,
                               int R, int C){
  tc_tile(src, dst, R, C, blockIdx.x, blockIdx.y, threadIdx.x, threadIdx.y);
}

// ---------------- embedding + positional encoding (bf16 stream only) ----------------
__global__ void embed_kernel(const int* __restrict__ x, const float* __restrict__ emb,
                             const float* __restrict__ pool, u16* __restrict__ hb){
  const int row = blockIdx.x;
  const int b = row / TT, t = row % TT;
  const int d0 = threadIdx.x * 4;
  float v[4];
  if (t == 0){
    const float4 p4 = *(const float4*)&pool[d0];
    v[0] = p4.x; v[1] = p4.y; v[2] = p4.z; v[3] = p4.w;
  } else {
    const int id = x[b * SEQ + (t - 1)];
    const float4 e4 = *(const float4*)&emb[(size_t)id * D + d0];
    v[0] = e4.x * 32.f; v[1] = e4.y * 32.f; v[2] = e4.z * 32.f; v[3] = e4.w * 32.f;
  }
  const float c = -logf(10000.f) / (float)D;
  float o[4];
  #pragma unroll
  for (int j = 0; j < 4; j++){
    const int d = d0 + j;
    const int p = d >> 1;
    const float freq = expf((float)(2 * p) * c);
    const float ang = (float)t * freq;
    const float pe = (d & 1) ? cosf(ang) : sinf(ang);
    o[j] = v[j] + pe;
  }
  const unsigned int lo = (unsigned)f2bf(o[0]) | ((unsigned)f2bf(o[1]) << 16);
  const unsigned int hi = (unsigned)f2bf(o[2]) | ((unsigned)f2bf(o[3]) << 16);
  *(uint2*)&hb[(size_t)row * D + d0] = make_uint2(lo, hi);
}

// ---------------- fused residual + LayerNorm (all-bf16 stream) ----------------
__global__ void ln_kernel(u16* __restrict__ hio, const u16* __restrict__ res,
                          const float* __restrict__ g, const float* __restrict__ bta){
  const int row = blockIdx.x;
  const int tid = threadIdx.x;
  const size_t off = (size_t)row * D + tid * 4;
  const uint2 a2 = *(const uint2*)&hio[off];
  const uint2 r2 = *(const uint2*)&res[off];
  const float s0 = bf2f((u16)(a2.x & 0xffff)) + bf2f((u16)(r2.x & 0xffff));
  const float s1 = bf2f((u16)(a2.x >> 16))    + bf2f((u16)(r2.x >> 16));
  const float s2 = bf2f((u16)(a2.y & 0xffff)) + bf2f((u16)(r2.y & 0xffff));
  const float s3 = bf2f((u16)(a2.y >> 16))    + bf2f((u16)(r2.y >> 16));
  float sum = s0 + s1 + s2 + s3;
  float sq = s0*s0 + s1*s1 + s2*s2 + s3*s3;
  #pragma unroll
  for (int m = 32; m >= 1; m >>= 1){ sum += __shfl_xor(sum, m); sq += __shfl_xor(sq, m); }
  __shared__ float red[2][4];
  const int w = tid >> 6;
  if ((tid & 63) == 0){ red[0][w] = sum; red[1][w] = sq; }
  __syncthreads();
  sum = red[0][0] + red[0][1] + red[0][2] + red[0][3];
  sq  = red[1][0] + red[1][1] + red[1][2] + red[1][3];
  const float mean = sum * (1.f / D);
  const float var = sq * (1.f / D) - mean * mean;
  const float rs = rsqrtf(var + 1e-5f);
  const float4 gv = *(const float4*)&g[tid * 4];
  const float4 bv = *(const float4*)&bta[tid * 4];
  const float o0 = (s0 - mean) * rs * gv.x + bv.x;
  const float o1 = (s1 - mean) * rs * gv.y + bv.y;
  const float o2 = (s2 - mean) * rs * gv.z + bv.z;
  const float o3 = (s3 - mean) * rs * gv.w + bv.w;
  const unsigned int lo = (unsigned)f2bf(o0) | ((unsigned)f2bf(o1) << 16);
  const unsigned int hi = (unsigned)f2bf(o2) | ((unsigned)f2bf(o3) << 16);
  *(uint2*)&hio[off] = make_uint2(lo, hi);
}

// ---------------- MFMA attention: one block (4 waves) per (batch, head) ----------------
__global__ __launch_bounds__(256) void attn_kernel(const u16* __restrict__ qkv,
    const float* __restrict__ rel, u16* __restrict__ ctxb){
  __shared__ u16 Qf[8 * 81 * 8];
  __shared__ u16 Kf[8 * 81 * 8];
  __shared__ u16 Vf[12 * 65 * 8];
  __shared__ u16 Pf[12 * 81 * 8];
  __shared__ float Ss[TP][84];
  const int bh = blockIdx.x;
  const int b = bh >> 4, hh = bh & 15;
  const int tid = threadIdx.x, w = tid >> 6, l = tid & 63;
  const size_t qvbase = (size_t)(b * TT) * QS + hh * DKH;
  const size_t obase  = (size_t)(b * TT) * D + hh * DKH;

  {
    const int r0 = tid >> 4, c4 = (tid & 15) * 4;
    const int g = c4 >> 3, e = c4 & 7;
    for (int r = r0; r < TP; r += 16){
      uint2 q2 = make_uint2(0u, 0u), k2 = make_uint2(0u, 0u);
      if (r < TT){
        q2 = *(const uint2*)&qkv[qvbase + (size_t)r * QS + c4];
        k2 = *(const uint2*)&qkv[qvbase + 1024 + (size_t)r * QS + c4];
      }
      *(uint2*)&Qf[(g * 81 + r) * 8 + e] = q2;
      *(uint2*)&Kf[(g * 81 + r) * 8 + e] = k2;
    }
    for (int j = r0; j < KP; j += 16){
      u16 v4[4] = {0, 0, 0, 0};
      if (j < TT) *(uint2*)v4 = *(const uint2*)&qkv[qvbase + 2048 + (size_t)j * QS + c4];
      const int gg = j >> 3, ee = j & 7;
      #pragma unroll
      for (int d = 0; d < 4; d++)
        Vf[(gg * 65 + (c4 + d)) * 8 + ee] = v4[d];
    }
  }
  __syncthreads();

  const int fr = l & 15, gg = l >> 4;
  for (int p = w; p < 25; p += 4){
    const int rt = p / 5, ct = p % 5;
    f32x4 acc = {};
    #pragma unroll
    for (int kk = 0; kk < 2; kk++){
      const short8 a  = *(const short8*)&Qf[((kk * 4 + gg) * 81 + rt * 16 + fr) * 8];
      const short8 bf = *(const short8*)&Kf[((kk * 4 + gg) * 81 + ct * 16 + fr) * 8];
      acc = __builtin_amdgcn_mfma_f32_16x16x32_bf16(a, bf, acc, 0, 0, 0);
    }
    const int col = ct * 16 + fr;
    #pragma unroll
    for (int r = 0; r < 4; r++){
      const int row = rt * 16 + gg * 4 + r;
      float sv = -1e30f;
      if (row < TT && col < TT)
        sv = acc[r] * 0.125f + rel[((size_t)hh * 78 + row) * 78 + col];
      Ss[row][col] = sv;
    }
  }
  __syncthreads();

  for (int row = w; row < TP; row += 4){
    const float s1 = Ss[row][l];
    const float s2 = (l < 16) ? Ss[row][64 + l] : -1e30f;
    float mx = fmaxf(s1, s2);
    #pragma unroll
    for (int m = 32; m >= 1; m >>= 1) mx = fmaxf(mx, __shfl_xor(mx, m));
    const float e1 = __expf(s1 - mx);
    const float e2 = (l < 16) ? __expf(s2 - mx) : 0.f;
    float sum = e1 + e2;
    #pragma unroll
    for (int m = 32; m >= 1; m >>= 1) sum += __shfl_xor(sum, m);
    const float inv = 1.f / sum;
    Pf[((l >> 3) * 81 + row) * 8 + (l & 7)] = f2bf(e1 * inv);
    if (l < 16){
      Pf[((8  + (l >> 3)) * 81 + row) * 8 + (l & 7)] = f2bf(e2 * inv);
      Pf[((10 + (l >> 3)) * 81 + row) * 8 + (l & 7)] = 0;
    }
  }
  __syncthreads();

  for (int p = w; p < 20; p += 4){
    const int rt = p >> 2, ct = p & 3;
    f32x4 acc = {};
    #pragma unroll
    for (int kk = 0; kk < 3; kk++){
      const short8 a  = *(const short8*)&Pf[((kk * 4 + gg) * 81 + rt * 16 + fr) * 8];
      const short8 bf = *(const short8*)&Vf[((kk * 4 + gg) * 65 + ct * 16 + fr) * 8];
      acc = __builtin_amdgcn_mfma_f32_16x16x32_bf16(a, bf, acc, 0, 0, 0);
    }
    #pragma unroll
    for (int r = 0; r < 4; r++){
      const int row = rt * 16 + gg * 4 + r;
      if (row < TT)
        ctxb[obase + (size_t)row * D + ct * 16 + fr] = f2bf(acc[r]);
    }
  }
}

// ---------------- 128x128 bf16 MFMA GEMM: dbuf + stage-ahead, XCD-chunked swizzle,
// LDS unit-XOR swizzle (both-sides): 16B unit u stored at u^((row>>1)&3) within its
// 64B row -> fragment-read lanes spread 2-per-bank (free) instead of 8-way conflict.
template<int OBF16, int BIAS, int GELU>
__global__ __launch_bounds__(256, 4) void gemm_bt(
    const u16* __restrict__ A, int lda,
    const u16* __restrict__ Bt,
    void* __restrict__ Cv, int ldc,
    const float* __restrict__ bias, int K, int nby)
{
  __shared__ u16 As[2][128 * 32];
  __shared__ u16 Bs[2][128 * 32];
  const int nwg = gridDim.x, bid = blockIdx.x;
  const int q8 = nwg >> 3, r8 = nwg & 7;
  const int xcd = bid & 7, off = bid >> 3;
  const int wg = (xcd < r8 ? xcd * (q8 + 1) : r8 * (q8 + 1) + (xcd - r8) * q8) + off;
  const int m0 = (wg / nby) * 128, n0 = (wg % nby) * 128;

  const int tid = threadIdx.x;
  const int l = tid & 63, w = tid >> 6;
  const int wr = w >> 1, wc = w & 1;
  f32x4 acc[4][4] = {};
  const int lr = l >> 2;
  // stage source col: unit (l&3) XOR'd by row-pair ((l>>3)&3) -> LDS holds swizzled layout
  const int lseg = ((l & 3) ^ ((l >> 3) & 3)) * 8;
  const u16* ga0 = A + (size_t)(m0 + w * 32 + lr) * lda + lseg;
  const u16* ga1 = A + (size_t)(m0 + w * 32 + 16 + lr) * lda + lseg;
  const u16* gb0 = Bt + (size_t)(n0 + w * 32 + lr) * K + lseg;
  const u16* gb1 = Bt + (size_t)(n0 + w * 32 + 16 + lr) * K + lseg;
  const int fr = l & 15;
  // frag read col: logical unit (l>>4) -> physical (l>>4) ^ ((row>>1)&3) = ^((l>>1)&3)
  const int kg = ((l >> 4) ^ ((l >> 1) & 3)) * 8;

#define STAGE(sel, kc) do { \
    gload16(ga0 + (kc), &As[sel][(w * 32) * 32]); \
    gload16(ga1 + (kc), &As[sel][(w * 32 + 16) * 32]); \
    gload16(gb0 + (kc), &Bs[sel][(w * 32) * 32]); \
    gload16(gb1 + (kc), &Bs[sel][(w * 32 + 16) * 32]); \
  } while (0)

  const int nkt = K >> 5;
  STAGE(0, 0);
  __syncthreads();
  int cur = 0;
  #pragma unroll 1
  for (int kt = 0; kt < nkt; ++kt){
    if (kt + 1 < nkt) STAGE(cur ^ 1, (kt + 1) * 32);
    short8 af[4], bf[4];
    #pragma unroll
    for (int i = 0; i < 4; i++){
      af[i] = *(const short8*)&As[cur][(wr * 64 + i * 16 + fr) * 32 + kg];
      bf[i] = *(const short8*)&Bs[cur][(wc * 64 + i * 16 + fr) * 32 + kg];
    }
    #pragma unroll
    for (int i = 0; i < 4; i++)
      #pragma unroll
      for (int j = 0; j < 4; j++)
        acc[i][j] = __builtin_amdgcn_mfma_f32_16x16x32_bf16(af[i], bf[j], acc[i][j], 0, 0, 0);
    __syncthreads();
    cur ^= 1;
  }
#undef STAGE

  const int rg = (l >> 4) * 4;
  #pragma unroll
  for (int i = 0; i < 4; i++){
    #pragma unroll
    for (int j = 0; j < 4; j++){
      const int col = n0 + wc * 64 + j * 16 + fr;
      const float bv = BIAS ? bias[col] : 0.f;
      #pragma unroll
      for (int r = 0; r < 4; r++){
        const int row = m0 + wr * 64 + i * 16 + rg + r;
        float xv = acc[i][j][r] + bv;
        if (GELU) xv = 0.5f * xv * (1.f + erff(xv * 0.70710678118f));
        if (OBF16) ((u16*)Cv)[(size_t)row * ldc + col] = f2bf(xv);
        else       ((float*)Cv)[(size_t)row * ldc + col] = xv;
      }
    }
  }
}

extern "C" void kernel_launch(void* const* d_in, const int* in_sizes, int n_in,
                              void* d_out, int out_size, void* d_ws, size_t ws_size,
                              hipStream_t stream) {
  const int*   x       = (const int*)  d_in[0];
  const float* emb     = (const float*)d_in[1];
  const float* pool    = (const float*)d_in[2];
  const float* Wq      = (const float*)d_in[3];
  const float* Wk      = (const float*)d_in[4];
  const float* Wv      = (const float*)d_in[5];
  const float* Wo      = (const float*)d_in[6];
  const float* rel     = (const float*)d_in[7];
  const float* ln1_g   = (const float*)d_in[8];
  const float* ln1_b   = (const float*)d_in[9];
  const float* ln2_g   = (const float*)d_in[10];
  const float* ln2_b   = (const float*)d_in[11];
  const float* W1      = (const float*)d_in[12];
  const float* b1      = (const float*)d_in[13];
  const float* W2      = (const float*)d_in[14];
  const float* b2      = (const float*)d_in[15];
  const float* Wout    = (const float*)d_in[16];
  const float* bout    = (const float*)d_in[17];
  float* out = (float*)d_out;

  const size_t SZ_WDD  = (size_t)D * D * 2;
  const size_t SZ_WDF  = (size_t)D * DFF * 2;
  const size_t SZ_HB   = (size_t)ROWS * D * 2;
  const size_t need = 4*SZ_WDD + 3*SZ_WDF + 6*SZ_HB;
  if (ws_size < need) return;

  char* p = (char*)d_ws;
  u16* WqkvT = (u16*)p; p += 3*SZ_WDD;
  u16* WoT   = (u16*)p; p += SZ_WDD;
  u16* W1T   = (u16*)p; p += SZ_WDF;
  u16* W2T   = (u16*)p; p += SZ_WDF;
  u16* WouT  = (u16*)p; p += SZ_WDF;
  u16* hb    = (u16*)p; p += SZ_HB;
  u16* qkv   = (u16*)p; p += 3*SZ_HB;    // [ROWS][3072]
  u16* ctxb  = (u16*)p; p += SZ_HB;
  u16* gb    = qkv;                       // FFN hidden aliases qkv+ctx
  u16* tmpb  = (u16*)p; p += SZ_HB;       // residual-branch bf16

  dim3 tb(32, 8);
  transpose_cast<<<dim3(VOCAB/32, D/32), tb, 0, stream>>>(Wout, WouT, D, VOCAB);
  embed_kernel<<<ROWS, 256, 0, stream>>>(x, emb, pool, hb);

  const int MB = ROWS / 128;   // 134
  for (int l = 0; l < LAYERS; ++l){
    const size_t wo = (size_t)l * D * D;
    const size_t wf = (size_t)l * D * DFF;
    transpose6<<<12288, tb, 0, stream>>>(Wq + wo, Wk + wo, Wv + wo, Wo + wo,
                                         W1 + wf, W2 + wf, WqkvT, WoT, W1T, W2T);

    gemm_bt<1,0,0><<<MB * (QS/128),  256, 0, stream>>>(hb, D, WqkvT, qkv, QS, nullptr, D, QS/128);
    attn_kernel<<<BATCH*NH, 256, 0, stream>>>(qkv, rel + (size_t)l*NH*78*78, ctxb);
    gemm_bt<1,0,0><<<MB * (D/128),   256, 0, stream>>>(ctxb, D, WoT, tmpb, D, nullptr, D, D/128);
    ln_kernel<<<ROWS, 256, 0, stream>>>(hb, tmpb, ln1_g + l*D, ln1_b + l*D);
    gemm_bt<1,1,1><<<MB * (DFF/128), 256, 0, stream>>>(hb, D, W1T, gb, DFF, b1 + l*DFF, D, DFF/128);
    gemm_bt<1,1,0><<<MB * (D/128),   256, 0, stream>>>(gb, DFF, W2T, tmpb, D, b2 + l*D, DFF, D/128);
    ln_kernel<<<ROWS, 256, 0, stream>>>(hb, tmpb, ln2_g + l*D, ln2_b + l*D);
  }
  gemm_bt<0,1,0><<<(BATCH/128) * (VOCAB/128), 256, 0, stream>>>(
      hb, TT * D, WouT, out, VOCAB, bout, D, VOCAB/128);
}